// Round 1
// baseline (239.656 us; speedup 1.0000x reference)
//
#include <hip/hip_runtime.h>
#include <hip/hip_bf16.h>
#include <stdint.h>

typedef unsigned short u16;
typedef __attribute__((ext_vector_type(8))) short short8;
typedef __attribute__((ext_vector_type(4))) float f32x4;

#define B_DIM 4096
#define D_DIM 1024
#define H_DIM 1024
#define K_DIM 2048   // D + H
#define N_DIM 4096   // 4H
#define LN_EPS 1e-5f

// ---------- helpers ----------
__device__ __forceinline__ u16 f2bf(float f) {
    union { float f; uint32_t u; } v; v.f = f;
    uint32_t u = v.u;
    uint32_t r = (u + 0x7FFFu + ((u >> 16) & 1u)) >> 16;  // RNE
    return (u16)r;
}
__device__ __forceinline__ float bf2f(u16 h) {
    union { uint32_t u; float f; } v; v.u = ((uint32_t)h) << 16;
    return v.f;
}
__device__ __forceinline__ void gld16(const u16* g, u16* l) {
    __builtin_amdgcn_global_load_lds(
        (const __attribute__((address_space(1))) void*)g,
        (__attribute__((address_space(3))) void*)l,
        16, 0, 0);
}
__device__ __forceinline__ float sigm(float x) { return 1.0f / (1.0f + __expf(-x)); }
__device__ __forceinline__ float tanh_fast(float x) { return 1.0f - 2.0f / (__expf(2.0f * x) + 1.0f); }

// ---------- kernel 1: cast+concat A = [x | prev_h] -> bf16 [4096][2048] ----------
__global__ __launch_bounds__(256) void cast_concat_A(const float* __restrict__ x,
                                                     const float* __restrict__ h,
                                                     u16* __restrict__ A) {
    int id = blockIdx.x * 256 + threadIdx.x;     // 4096*256 threads, 8 elems each
    int row = id >> 8;
    int col = (id & 255) * 8;
    const float* src = (col < D_DIM) ? (x + (size_t)row * D_DIM + col)
                                     : (h + (size_t)row * H_DIM + (col - D_DIM));
    float4 v0 = ((const float4*)src)[0];
    float4 v1 = ((const float4*)src)[1];
    union { u16 us[8]; uint4 u; } p;
    p.us[0] = f2bf(v0.x); p.us[1] = f2bf(v0.y); p.us[2] = f2bf(v0.z); p.us[3] = f2bf(v0.w);
    p.us[4] = f2bf(v1.x); p.us[5] = f2bf(v1.y); p.us[6] = f2bf(v1.z); p.us[7] = f2bf(v1.w);
    *(uint4*)(A + (size_t)id * 8) = p.u;
}

// ---------- kernel 2: cast+transpose B: Bt[n][k] = Wcomb[k][n] -> bf16 [4096][2048] ----------
__global__ __launch_bounds__(256) void cast_transpose_B(const float* __restrict__ Wx,
                                                        const float* __restrict__ Wh,
                                                        u16* __restrict__ Bt) {
    __shared__ u16 tile[64][72];                 // [n_local][k_local], padded
    int n0 = blockIdx.x * 64;
    int k0 = blockIdx.y * 64;
    int t = threadIdx.x;
    int nl4 = (t & 15) * 4;
    int kl  = t >> 4;                            // 0..15
#pragma unroll
    for (int it = 0; it < 4; ++it) {
        int kli = kl + it * 16;
        int k = k0 + kli;
        const float* src = (k < D_DIM) ? (Wx + (size_t)k * N_DIM)
                                       : (Wh + (size_t)(k - D_DIM) * N_DIM);
        float4 v = *(const float4*)(src + n0 + nl4);
        tile[nl4 + 0][kli] = f2bf(v.x);
        tile[nl4 + 1][kli] = f2bf(v.y);
        tile[nl4 + 2][kli] = f2bf(v.z);
        tile[nl4 + 3][kli] = f2bf(v.w);
    }
    __syncthreads();
    int nl = t >> 2;
    int kp = (t & 3) * 16;
    uint4 a = *(const uint4*)&tile[nl][kp];
    uint4 b = *(const uint4*)&tile[nl][kp + 8];
    u16* dst = Bt + (size_t)(n0 + nl) * K_DIM + k0 + kp;
    *(uint4*)dst = a;
    *(uint4*)(dst + 8) = b;
}

// ---------- kernel 3: GEMM a = A @ Bt^T + bias -> bf16 [4096][4096] (m97 structure) ----------
__global__ __launch_bounds__(256) void gemm_bf16(const u16* __restrict__ A,   // [4096][2048]
                                                 const u16* __restrict__ Bt,  // [4096][2048]
                                                 const float* __restrict__ bias,
                                                 u16* __restrict__ C) {       // [4096][4096]
    __shared__ u16 As[128 * 32];
    __shared__ u16 Bs[128 * 32];
    const int m0 = blockIdx.y * 128;
    const int n0 = blockIdx.x * 128;
    const int tid = threadIdx.x;
    const int wave = tid >> 6, lane = tid & 63;
    const int wm = (wave & 1) * 64, wn = (wave >> 1) * 64;

    f32x4 acc[4][4] = {};

    // staging addresses: each wave stages 32 rows of each tile (2 issues of 16 rows)
    const int srow = wave * 32 + (lane >> 2);
    const int skc  = (lane & 3) * 8;
    const u16* aG = A  + (size_t)(m0 + srow) * K_DIM + skc;
    const u16* bG = Bt + (size_t)(n0 + srow) * K_DIM + skc;
    u16* aL = As + (wave * 32) * 32;   // HW adds lane*16B
    u16* bL = Bs + (wave * 32) * 32;

    for (int kt = 0; kt < K_DIM; kt += 32) {
        __syncthreads();
        gld16(aG + kt,                aL);
        gld16(aG + kt + 16 * K_DIM,   aL + 16 * 32);
        gld16(bG + kt,                bL);
        gld16(bG + kt + 16 * K_DIM,   bL + 16 * 32);
        __syncthreads();

        short8 af[4], bfr[4];
        const int krd = (lane >> 4) * 8;
#pragma unroll
        for (int i = 0; i < 4; ++i)
            af[i] = *(const short8*)(As + (wm + i * 16 + (lane & 15)) * 32 + krd);
#pragma unroll
        for (int j = 0; j < 4; ++j)
            bfr[j] = *(const short8*)(Bs + (wn + j * 16 + (lane & 15)) * 32 + krd);
#pragma unroll
        for (int i = 0; i < 4; ++i)
#pragma unroll
            for (int j = 0; j < 4; ++j)
                acc[i][j] = __builtin_amdgcn_mfma_f32_16x16x32_bf16(af[i], bfr[j], acc[i][j], 0, 0, 0);
    }

    // epilogue: C/D layout col=lane&15, row=(lane>>4)*4+reg  (m89/m91-verified)
#pragma unroll
    for (int i = 0; i < 4; ++i) {
        const int r0 = m0 + wm + i * 16 + (lane >> 4) * 4;
#pragma unroll
        for (int j = 0; j < 4; ++j) {
            const int c = n0 + wn + j * 16 + (lane & 15);
            const float bb = bias[c];
#pragma unroll
            for (int r = 0; r < 4; ++r)
                C[(size_t)(r0 + r) * N_DIM + c] = f2bf(acc[i][j][r] + bb);
        }
    }
}

// ---------- kernel 4: LayerNorm + gates + cell update ----------
__global__ __launch_bounds__(256) void ln_lstm(const u16* __restrict__ aT,     // [4096][4096] bf16
                                               const float* __restrict__ pc,   // prev_c
                                               const float* __restrict__ gamma,
                                               const float* __restrict__ beta,
                                               float* __restrict__ out) {      // [h | c]
    const int row = blockIdx.x;
    const int t = threadIdx.x;
    const u16* ar = aT + (size_t)row * N_DIM;

    float sum = 0.f, ssq = 0.f;
#pragma unroll
    for (int p = 0; p < 2; ++p) {
        union { uint4 u; u16 us[8]; } raw;
        raw.u = *(const uint4*)(ar + p * 2048 + t * 8);
#pragma unroll
        for (int e = 0; e < 8; ++e) { float v = bf2f(raw.us[e]); sum += v; ssq += v * v; }
    }
#pragma unroll
    for (int off = 32; off > 0; off >>= 1) {
        sum += __shfl_down(sum, off, 64);
        ssq += __shfl_down(ssq, off, 64);
    }
    __shared__ float red[8];
    if ((t & 63) == 0) { red[t >> 6] = sum; red[4 + (t >> 6)] = ssq; }
    __syncthreads();
    const float ts = red[0] + red[1] + red[2] + red[3];
    const float tq = red[4] + red[5] + red[6] + red[7];
    const float mu = ts * (1.0f / N_DIM);
    const float var = fmaxf(tq * (1.0f / N_DIM) - mu * mu, 0.0f);
    const float rs = rsqrtf(var + LN_EPS);

    const int j0 = t * 4;
    float vi[4], vf[4], vo[4], vg[4];
    auto gate = [&](int off, float* v) {
        union { uint2 u; u16 us[4]; } raw;
        raw.u = *(const uint2*)(ar + off + j0);
        float4 gm = *(const float4*)(gamma + off + j0);
        float4 bt = *(const float4*)(beta + off + j0);
        v[0] = (bf2f(raw.us[0]) - mu) * rs * gm.x + bt.x;
        v[1] = (bf2f(raw.us[1]) - mu) * rs * gm.y + bt.y;
        v[2] = (bf2f(raw.us[2]) - mu) * rs * gm.z + bt.z;
        v[3] = (bf2f(raw.us[3]) - mu) * rs * gm.w + bt.w;
    };
    gate(0, vi); gate(1024, vf); gate(2048, vo); gate(3072, vg);

    float4 c4 = *(const float4*)(pc + (size_t)row * H_DIM + j0);
    float cin[4] = {c4.x, c4.y, c4.z, c4.w};
    float nh[4], nc[4];
#pragma unroll
    for (int r = 0; r < 4; ++r) {
        float ig = sigm(vi[r]);
        float fg = sigm(vf[r]);
        float og = sigm(vo[r]);
        float gg = tanh_fast(vg[r]);
        nc[r] = fg * cin[r] + ig * gg;
        nh[r] = og * tanh_fast(nc[r]);
    }
    float4 h4 = {nh[0], nh[1], nh[2], nh[3]};
    float4 c4o = {nc[0], nc[1], nc[2], nc[3]};
    *(float4*)(out + (size_t)row * H_DIM + j0) = h4;
    *(float4*)(out + (size_t)B_DIM * H_DIM + (size_t)row * H_DIM + j0) = c4o;
}

// ---------- launch ----------
extern "C" void kernel_launch(void* const* d_in, const int* in_sizes, int n_in,
                              void* d_out, int out_size, void* d_ws, size_t ws_size,
                              hipStream_t stream) {
    const float* x  = (const float*)d_in[0];
    const float* ph = (const float*)d_in[1];
    const float* pc = (const float*)d_in[2];
    const float* Wx = (const float*)d_in[3];
    const float* Wh = (const float*)d_in[4];
    const float* b  = (const float*)d_in[5];
    const float* gm = (const float*)d_in[6];
    const float* bt = (const float*)d_in[7];
    float* out = (float*)d_out;

    char* ws = (char*)d_ws;
    u16* Abf = (u16*)ws;                               // 16 MiB: [4096][2048] bf16
    u16* Btb = (u16*)(ws + (size_t)16 * 1024 * 1024);  // 16 MiB: [4096][2048] bf16
    u16* aT  = (u16*)(ws + (size_t)32 * 1024 * 1024);  // 32 MiB: [4096][4096] bf16

    cast_concat_A<<<dim3(4096), dim3(256), 0, stream>>>(x, ph, Abf);
    cast_transpose_B<<<dim3(64, 32), dim3(256), 0, stream>>>(Wx, Wh, Btb);
    gemm_bf16<<<dim3(32, 32), dim3(256), 0, stream>>>(Abf, Btb, b, aT);
    ln_lstm<<<dim3(4096), dim3(256), 0, stream>>>(aT, pc, gm, bt, out);
}

// Round 2
// 235.221 us; speedup vs baseline: 1.0189x; 1.0189x over previous
//
#include <hip/hip_runtime.h>
#include <hip/hip_bf16.h>
#include <stdint.h>

typedef unsigned short u16;
typedef __attribute__((ext_vector_type(8))) short short8;
typedef __attribute__((ext_vector_type(4))) float f32x4;

#define B_DIM 4096
#define D_DIM 1024
#define H_DIM 1024
#define K_DIM 2048   // D + H
#define N_DIM 4096   // 4H
#define LN_EPS 1e-5f

// ---------- helpers ----------
__device__ __forceinline__ u16 f2bf(float f) {
    union { float f; uint32_t u; } v; v.f = f;
    uint32_t u = v.u;
    uint32_t r = (u + 0x7FFFu + ((u >> 16) & 1u)) >> 16;  // RNE
    return (u16)r;
}
__device__ __forceinline__ float bf2f(u16 h) {
    union { uint32_t u; float f; } v; v.u = ((uint32_t)h) << 16;
    return v.f;
}
__device__ __forceinline__ void gld16(const u16* g, u16* l) {
    __builtin_amdgcn_global_load_lds(
        (const __attribute__((address_space(1))) void*)g,
        (__attribute__((address_space(3))) void*)l,
        16, 0, 0);
}
__device__ __forceinline__ float sigm(float x) { return 1.0f / (1.0f + __expf(-x)); }
__device__ __forceinline__ float tanh_fast(float x) { return 1.0f - 2.0f / (__expf(2.0f * x) + 1.0f); }

// ---------- kernel 1: cast+concat A = [x | prev_h] -> bf16 [4096][2048] ----------
__global__ __launch_bounds__(256) void cast_concat_A(const float* __restrict__ x,
                                                     const float* __restrict__ h,
                                                     u16* __restrict__ A) {
    int id = blockIdx.x * 256 + threadIdx.x;     // 4096*256 threads, 8 elems each
    int row = id >> 8;
    int col = (id & 255) * 8;
    const float* src = (col < D_DIM) ? (x + (size_t)row * D_DIM + col)
                                     : (h + (size_t)row * H_DIM + (col - D_DIM));
    float4 v0 = ((const float4*)src)[0];
    float4 v1 = ((const float4*)src)[1];
    union { u16 us[8]; uint4 u; } p;
    p.us[0] = f2bf(v0.x); p.us[1] = f2bf(v0.y); p.us[2] = f2bf(v0.z); p.us[3] = f2bf(v0.w);
    p.us[4] = f2bf(v1.x); p.us[5] = f2bf(v1.y); p.us[6] = f2bf(v1.z); p.us[7] = f2bf(v1.w);
    *(uint4*)(A + (size_t)id * 8) = p.u;
}

// ---------- kernel 2: cast+transpose B: Bt[n][k] = Wcomb[k][n] -> bf16 [4096][2048] ----------
// LDS layout: tile[k][n ^ swz(k)], swz(k) = 8*((k>>4)&3). Writes are packed uint2
// (row-contiguous -> conflict-free); reads are scalar u16 but swizzle spreads
// lanes' k-blocks across bank groups (<=2-way, free per m136).
__global__ __launch_bounds__(256) void cast_transpose_B(const float* __restrict__ Wx,
                                                        const float* __restrict__ Wh,
                                                        u16* __restrict__ Bt) {
    __shared__ u16 tile[64 * 64];
    const int n0 = blockIdx.x * 64;
    const int k0 = blockIdx.y * 64;
    const int t = threadIdx.x;
    const int kl  = t >> 4;            // 0..15
    const int nl4 = (t & 15) * 4;      // 0..60
#pragma unroll
    for (int it = 0; it < 4; ++it) {
        const int klocal = kl + it * 16;
        const int k = k0 + klocal;
        const float* src = (k < D_DIM) ? (Wx + (size_t)k * N_DIM)
                                       : (Wh + (size_t)(k - D_DIM) * N_DIM);
        float4 v = *(const float4*)(src + n0 + nl4);
        union { u16 us[4]; uint2 u; } p;
        p.us[0] = f2bf(v.x); p.us[1] = f2bf(v.y); p.us[2] = f2bf(v.z); p.us[3] = f2bf(v.w);
        const int swz = 8 * ((klocal >> 4) & 3);   // = 8*it
        *(uint2*)(tile + klocal * 64 + (nl4 ^ swz)) = p.u;
    }
    __syncthreads();
    const int nl = t >> 2;             // 0..63
    const int kp = (t & 3) * 16;       // 0..48
    const int swz = 8 * (t & 3);       // (kp+i)>>4 == t&3 for i<16
    union { u16 us[16]; uint4 q[2]; } o;
#pragma unroll
    for (int i = 0; i < 16; ++i)
        o.us[i] = tile[(kp + i) * 64 + (nl ^ swz)];
    u16* dst = Bt + (size_t)(n0 + nl) * K_DIM + k0 + kp;
    *(uint4*)dst = o.q[0];
    *(uint4*)(dst + 8) = o.q[1];
}

// ---------- kernel 3: GEMM a = A @ Bt^T + bias -> bf16 [4096][4096] (m97 structure) ----------
// LDS column-block XOR swizzle: LDS[r][kbl] holds global k-block (kbl - (r>>1)) & 3
// (r = row % 16). Staging picks the source block per lane; fragment reads invert it.
// This spreads half-wave ds_read_b128 across all bank quads (4/quad = min cycles).
__global__ __launch_bounds__(256) void gemm_bf16(const u16* __restrict__ A,   // [4096][2048]
                                                 const u16* __restrict__ Bt,  // [4096][2048]
                                                 const float* __restrict__ bias,
                                                 u16* __restrict__ C) {       // [4096][4096]
    __shared__ u16 As[128 * 32];
    __shared__ u16 Bs[128 * 32];
    const int m0 = blockIdx.y * 128;
    const int n0 = blockIdx.x * 128;
    const int tid = threadIdx.x;
    const int wave = tid >> 6, lane = tid & 63;
    const int wm = (wave & 1) * 64, wn = (wave >> 1) * 64;

    f32x4 acc[4][4] = {};

    // staging: local row r = lane>>2 (16-aligned chunks), LDS block kbl = lane&3.
    // fetch global block kbg = (kbl - (r>>1)) & 3  ->  skc = kbg*8
    const int srow = wave * 32 + (lane >> 2);
    const int skc  = (((lane & 3) - ((lane >> 3) & 3)) & 3) * 8;
    const u16* aG = A  + (size_t)(m0 + srow) * K_DIM + skc;
    const u16* bG = Bt + (size_t)(n0 + srow) * K_DIM + skc;
    u16* aL = As + (wave * 32) * 32;   // HW adds lane*16B
    u16* bL = Bs + (wave * 32) * 32;

    // fragment read: row lr = lane&15, want global block g = lane>>4
    // -> LDS block kbl = (g + (lr>>1)) & 3
    const int lr  = lane & 15;
    const int krd = (((lane >> 4) + (lr >> 1)) & 3) * 8;

    for (int kt = 0; kt < K_DIM; kt += 32) {
        __syncthreads();
        gld16(aG + kt,                aL);
        gld16(aG + kt + 16 * K_DIM,   aL + 16 * 32);
        gld16(bG + kt,                bL);
        gld16(bG + kt + 16 * K_DIM,   bL + 16 * 32);
        __syncthreads();

        short8 af[4], bfr[4];
#pragma unroll
        for (int i = 0; i < 4; ++i)
            af[i] = *(const short8*)(As + (wm + i * 16 + lr) * 32 + krd);
#pragma unroll
        for (int j = 0; j < 4; ++j)
            bfr[j] = *(const short8*)(Bs + (wn + j * 16 + lr) * 32 + krd);
#pragma unroll
        for (int i = 0; i < 4; ++i)
#pragma unroll
            for (int j = 0; j < 4; ++j)
                acc[i][j] = __builtin_amdgcn_mfma_f32_16x16x32_bf16(af[i], bfr[j], acc[i][j], 0, 0, 0);
    }

    // epilogue: C/D layout col=lane&15, row=(lane>>4)*4+reg  (m89/m91-verified)
#pragma unroll
    for (int i = 0; i < 4; ++i) {
        const int r0 = m0 + wm + i * 16 + (lane >> 4) * 4;
#pragma unroll
        for (int j = 0; j < 4; ++j) {
            const int c = n0 + wn + j * 16 + (lane & 15);
            const float bb = bias[c];
#pragma unroll
            for (int r = 0; r < 4; ++r)
                C[(size_t)(r0 + r) * N_DIM + c] = f2bf(acc[i][j][r] + bb);
        }
    }
}

// ---------- kernel 4: LayerNorm + gates + cell update (single pass over aT) ----------
__global__ __launch_bounds__(256) void ln_lstm(const u16* __restrict__ aT,     // [4096][4096] bf16
                                               const float* __restrict__ pc,   // prev_c
                                               const float* __restrict__ gamma,
                                               const float* __restrict__ beta,
                                               float* __restrict__ out) {      // [h | c]
    const int row = blockIdx.x;
    const int t = threadIdx.x;
    const u16* ar = aT + (size_t)row * N_DIM;
    const int j0 = t * 4;

    // one load per element: 4 gate slices x 4 elements, kept in registers
    union U2 { uint2 u; u16 us[4]; };
    U2 g4[4];
#pragma unroll
    for (int s = 0; s < 4; ++s) g4[s].u = *(const uint2*)(ar + s * H_DIM + j0);

    float sum = 0.f, ssq = 0.f;
#pragma unroll
    for (int s = 0; s < 4; ++s)
#pragma unroll
        for (int e = 0; e < 4; ++e) { float v = bf2f(g4[s].us[e]); sum += v; ssq += v * v; }

#pragma unroll
    for (int off = 32; off > 0; off >>= 1) {
        sum += __shfl_down(sum, off, 64);
        ssq += __shfl_down(ssq, off, 64);
    }
    __shared__ float red[8];
    if ((t & 63) == 0) { red[t >> 6] = sum; red[4 + (t >> 6)] = ssq; }
    __syncthreads();
    const float ts = red[0] + red[1] + red[2] + red[3];
    const float tq = red[4] + red[5] + red[6] + red[7];
    const float mu = ts * (1.0f / N_DIM);
    const float var = fmaxf(tq * (1.0f / N_DIM) - mu * mu, 0.0f);
    const float rs = rsqrtf(var + LN_EPS);

    float vi[4], vf[4], vo[4], vg[4];
    auto gate = [&](int s, float* v) {
        const int off = s * H_DIM;
        float4 gm = *(const float4*)(gamma + off + j0);
        float4 bt = *(const float4*)(beta + off + j0);
        v[0] = (bf2f(g4[s].us[0]) - mu) * rs * gm.x + bt.x;
        v[1] = (bf2f(g4[s].us[1]) - mu) * rs * gm.y + bt.y;
        v[2] = (bf2f(g4[s].us[2]) - mu) * rs * gm.z + bt.z;
        v[3] = (bf2f(g4[s].us[3]) - mu) * rs * gm.w + bt.w;
    };
    gate(0, vi); gate(1, vf); gate(2, vo); gate(3, vg);

    float4 c4 = *(const float4*)(pc + (size_t)row * H_DIM + j0);
    float cin[4] = {c4.x, c4.y, c4.z, c4.w};
    float nh[4], nc[4];
#pragma unroll
    for (int r = 0; r < 4; ++r) {
        float ig = sigm(vi[r]);
        float fg = sigm(vf[r]);
        float og = sigm(vo[r]);
        float gg = tanh_fast(vg[r]);
        nc[r] = fg * cin[r] + ig * gg;
        nh[r] = og * tanh_fast(nc[r]);
    }
    float4 h4 = {nh[0], nh[1], nh[2], nh[3]};
    float4 c4o = {nc[0], nc[1], nc[2], nc[3]};
    *(float4*)(out + (size_t)row * H_DIM + j0) = h4;
    *(float4*)(out + (size_t)B_DIM * H_DIM + (size_t)row * H_DIM + j0) = c4o;
}

// ---------- launch ----------
extern "C" void kernel_launch(void* const* d_in, const int* in_sizes, int n_in,
                              void* d_out, int out_size, void* d_ws, size_t ws_size,
                              hipStream_t stream) {
    const float* x  = (const float*)d_in[0];
    const float* ph = (const float*)d_in[1];
    const float* pc = (const float*)d_in[2];
    const float* Wx = (const float*)d_in[3];
    const float* Wh = (const float*)d_in[4];
    const float* b  = (const float*)d_in[5];
    const float* gm = (const float*)d_in[6];
    const float* bt = (const float*)d_in[7];
    float* out = (float*)d_out;

    char* ws = (char*)d_ws;
    u16* Abf = (u16*)ws;                               // 16 MiB: [4096][2048] bf16
    u16* Btb = (u16*)(ws + (size_t)16 * 1024 * 1024);  // 16 MiB: [4096][2048] bf16
    u16* aT  = (u16*)(ws + (size_t)32 * 1024 * 1024);  // 32 MiB: [4096][4096] bf16

    cast_concat_A<<<dim3(4096), dim3(256), 0, stream>>>(x, ph, Abf);
    cast_transpose_B<<<dim3(64, 32), dim3(256), 0, stream>>>(Wx, Wh, Btb);
    gemm_bf16<<<dim3(32, 32), dim3(256), 0, stream>>>(Abf, Btb, b, aT);
    ln_lstm<<<dim3(4096), dim3(256), 0, stream>>>(aT, pc, gm, bt, out);
}

// Round 3
// 229.457 us; speedup vs baseline: 1.0445x; 1.0251x over previous
//
#include <hip/hip_runtime.h>
#include <hip/hip_bf16.h>
#include <stdint.h>

typedef unsigned short u16;
typedef __attribute__((ext_vector_type(8))) short short8;
typedef __attribute__((ext_vector_type(16))) float f32x16;

#define B_DIM 4096
#define D_DIM 1024
#define H_DIM 1024
#define K_DIM 2048   // D + H
#define N_DIM 4096   // 4H
#define LN_EPS 1e-5f

// ---------- helpers ----------
__device__ __forceinline__ u16 f2bf(float f) {
    union { float f; uint32_t u; } v; v.f = f;
    uint32_t u = v.u;
    uint32_t r = (u + 0x7FFFu + ((u >> 16) & 1u)) >> 16;  // RNE
    return (u16)r;
}
__device__ __forceinline__ float bf2f(u16 h) {
    union { uint32_t u; float f; } v; v.u = ((uint32_t)h) << 16;
    return v.f;
}
__device__ __forceinline__ void gld16(const u16* g, u16* l) {
    __builtin_amdgcn_global_load_lds(
        (const __attribute__((address_space(1))) void*)g,
        (__attribute__((address_space(3))) void*)l,
        16, 0, 0);
}
__device__ __forceinline__ float sigm(float x) { return 1.0f / (1.0f + __expf(-x)); }
__device__ __forceinline__ float tanh_fast(float x) { return 1.0f - 2.0f / (__expf(2.0f * x) + 1.0f); }

// ---------- kernel 1: fused prep ----------
// blocks [0,4096): cast+concat A = [x | prev_h] -> bf16 [4096][2048]
// blocks [4096,6144): cast+transpose Bt[n][k] = Wcomb[k][n] -> bf16 [4096][2048]
__global__ __launch_bounds__(256) void prep(const float* __restrict__ x,
                                            const float* __restrict__ h,
                                            const float* __restrict__ Wx,
                                            const float* __restrict__ Wh,
                                            u16* __restrict__ A,
                                            u16* __restrict__ Bt) {
    __shared__ u16 tile[64 * 64];
    const int t = threadIdx.x;
    if (blockIdx.x < 4096) {
        int id = blockIdx.x * 256 + t;
        int row = id >> 8;
        int col = (id & 255) * 8;
        const float* src = (col < D_DIM) ? (x + (size_t)row * D_DIM + col)
                                         : (h + (size_t)row * H_DIM + (col - D_DIM));
        float4 v0 = ((const float4*)src)[0];
        float4 v1 = ((const float4*)src)[1];
        union { u16 us[8]; uint4 u; } p;
        p.us[0] = f2bf(v0.x); p.us[1] = f2bf(v0.y); p.us[2] = f2bf(v0.z); p.us[3] = f2bf(v0.w);
        p.us[4] = f2bf(v1.x); p.us[5] = f2bf(v1.y); p.us[6] = f2bf(v1.z); p.us[7] = f2bf(v1.w);
        *(uint4*)(A + (size_t)id * 8) = p.u;
    } else {
        // transpose tile: LDS layout tile[k][n ^ swz(k)], swz(k)=8*((k>>4)&3)
        const int v = blockIdx.x - 4096;       // 0..2047 = 64 x 32
        const int n0 = (v & 63) * 64;
        const int k0 = (v >> 6) * 64;
        const int kl  = t >> 4;                // 0..15
        const int nl4 = (t & 15) * 4;          // 0..60
#pragma unroll
        for (int it = 0; it < 4; ++it) {
            const int klocal = kl + it * 16;
            const int k = k0 + klocal;
            const float* src = (k < D_DIM) ? (Wx + (size_t)k * N_DIM)
                                           : (Wh + (size_t)(k - D_DIM) * N_DIM);
            float4 w = *(const float4*)(src + n0 + nl4);
            union { u16 us[4]; uint2 u; } p;
            p.us[0] = f2bf(w.x); p.us[1] = f2bf(w.y); p.us[2] = f2bf(w.z); p.us[3] = f2bf(w.w);
            const int swz = 8 * ((klocal >> 4) & 3);
            *(uint2*)(tile + klocal * 64 + (nl4 ^ swz)) = p.u;
        }
        __syncthreads();
        const int nl = t >> 2;
        const int kp = (t & 3) * 16;
        const int swz = 8 * (t & 3);
        union { u16 us[16]; uint4 q[2]; } o;
#pragma unroll
        for (int i = 0; i < 16; ++i)
            o.us[i] = tile[(kp + i) * 64 + (nl ^ swz)];
        u16* dst = Bt + (size_t)(n0 + nl) * K_DIM + k0 + kp;
        *(uint4*)dst = o.q[0];
        *(uint4*)(dst + 8) = o.q[1];
    }
}

// ---------- kernel 2: GEMM a = A @ Bt^T + bias -> bf16 [4096][4096] ----------
// BK=64 (32 KB LDS), 32x32x16 bf16 MFMA, 128x128 tile, 4 waves x (2x2 32-tiles).
// LDS column-block XOR swizzle (8 blocks of 16B per 128B row):
//   LDS[r][kbl] holds global k-block (kbl - (r&7)) & 7; reads invert it.
//   Fragment read bank-quad = (g + (r&7))&7 -> 4 lanes/quad = conflict-free min.
__global__ __launch_bounds__(256) void gemm_bf16(const u16* __restrict__ A,   // [4096][2048]
                                                 const u16* __restrict__ Bt,  // [4096][2048]
                                                 const float* __restrict__ bias,
                                                 u16* __restrict__ C) {       // [4096][4096]
    __shared__ u16 As[128 * 64];
    __shared__ u16 Bs[128 * 64];
    const int m0 = blockIdx.y * 128;
    const int n0 = blockIdx.x * 128;
    const int tid = threadIdx.x;
    const int wave = tid >> 6, lane = tid & 63;
    const int wm = (wave & 1) * 64, wn = (wave >> 1) * 64;

    f32x16 acc[2][2] = {};

    // staging: 4 issues/wave/matrix; issue q covers rows wave*32+q*8+(lane>>3),
    // LDS block kbl = lane&7 holds global block kbg = (kbl - (r&7)) & 7
    const int kbg = ((lane & 7) - ((lane >> 3) & 7)) & 7;
    const int skc = kbg * 8;
    const u16* aG = A  + (size_t)(m0 + wave * 32 + (lane >> 3)) * K_DIM + skc;
    const u16* bG = Bt + (size_t)(n0 + wave * 32 + (lane >> 3)) * K_DIM + skc;
    u16* aL = As + (wave * 32) * 64;   // HW adds lane*16B
    u16* bL = Bs + (wave * 32) * 64;

    const int lr = lane & 31;          // row within a 32-row block
    const int half = lane >> 5;        // 0/1 -> k-halves
    const u16* aFbase = As + (size_t)(wm + lr) * 64;
    const u16* bFbase = Bs + (size_t)(wn + lr) * 64;

    for (int kt = 0; kt < K_DIM; kt += 64) {
        __syncthreads();
#pragma unroll
        for (int q = 0; q < 4; ++q) {
            gld16(aG + kt + (size_t)q * 8 * K_DIM, aL + q * 8 * 64);
            gld16(bG + kt + (size_t)q * 8 * K_DIM, bL + q * 8 * 64);
        }
        __syncthreads();

#pragma unroll
        for (int kk = 0; kk < 4; ++kk) {
            const int koff = (((kk * 2 + half) + (lr & 7)) & 7) * 8;
            short8 af[2], bf[2];
#pragma unroll
            for (int i = 0; i < 2; ++i)
                af[i] = *(const short8*)(aFbase + i * 32 * 64 + koff);
#pragma unroll
            for (int j = 0; j < 2; ++j)
                bf[j] = *(const short8*)(bFbase + j * 32 * 64 + koff);
#pragma unroll
            for (int i = 0; i < 2; ++i)
#pragma unroll
                for (int j = 0; j < 2; ++j)
                    acc[i][j] = __builtin_amdgcn_mfma_f32_32x32x16_bf16(af[i], bf[j], acc[i][j], 0, 0, 0);
        }
    }

    // epilogue: 32x32 C/D layout col=lane&31, row=(reg&3)+8*(reg>>2)+4*(lane>>5)
#pragma unroll
    for (int i = 0; i < 2; ++i) {
#pragma unroll
        for (int j = 0; j < 2; ++j) {
            const int c = n0 + wn + 32 * j + lr;
            const float bb = bias[c];
#pragma unroll
            for (int reg = 0; reg < 16; ++reg) {
                const int row = m0 + wm + 32 * i + (reg & 3) + 8 * (reg >> 2) + 4 * half;
                C[(size_t)row * N_DIM + c] = f2bf(acc[i][j][reg] + bb);
            }
        }
    }
}

// ---------- kernel 3: LayerNorm + gates + cell update (single pass over aT) ----------
__global__ __launch_bounds__(256) void ln_lstm(const u16* __restrict__ aT,     // [4096][4096] bf16
                                               const float* __restrict__ pc,   // prev_c
                                               const float* __restrict__ gamma,
                                               const float* __restrict__ beta,
                                               float* __restrict__ out) {      // [h | c]
    const int row = blockIdx.x;
    const int t = threadIdx.x;
    const u16* ar = aT + (size_t)row * N_DIM;
    const int j0 = t * 4;

    union U2 { uint2 u; u16 us[4]; };
    U2 g4[4];
#pragma unroll
    for (int s = 0; s < 4; ++s) g4[s].u = *(const uint2*)(ar + s * H_DIM + j0);

    float sum = 0.f, ssq = 0.f;
#pragma unroll
    for (int s = 0; s < 4; ++s)
#pragma unroll
        for (int e = 0; e < 4; ++e) { float v = bf2f(g4[s].us[e]); sum += v; ssq += v * v; }

#pragma unroll
    for (int off = 32; off > 0; off >>= 1) {
        sum += __shfl_down(sum, off, 64);
        ssq += __shfl_down(ssq, off, 64);
    }
    __shared__ float red[8];
    if ((t & 63) == 0) { red[t >> 6] = sum; red[4 + (t >> 6)] = ssq; }
    __syncthreads();
    const float ts = red[0] + red[1] + red[2] + red[3];
    const float tq = red[4] + red[5] + red[6] + red[7];
    const float mu = ts * (1.0f / N_DIM);
    const float var = fmaxf(tq * (1.0f / N_DIM) - mu * mu, 0.0f);
    const float rs = rsqrtf(var + LN_EPS);

    float vi[4], vf[4], vo[4], vg[4];
    auto gate = [&](int s, float* v) {
        const int off = s * H_DIM;
        float4 gm = *(const float4*)(gamma + off + j0);
        float4 bt = *(const float4*)(beta + off + j0);
        v[0] = (bf2f(g4[s].us[0]) - mu) * rs * gm.x + bt.x;
        v[1] = (bf2f(g4[s].us[1]) - mu) * rs * gm.y + bt.y;
        v[2] = (bf2f(g4[s].us[2]) - mu) * rs * gm.z + bt.z;
        v[3] = (bf2f(g4[s].us[3]) - mu) * rs * gm.w + bt.w;
    };
    gate(0, vi); gate(1, vf); gate(2, vo); gate(3, vg);

    float4 c4 = *(const float4*)(pc + (size_t)row * H_DIM + j0);
    float cin[4] = {c4.x, c4.y, c4.z, c4.w};
    float nh[4], nc[4];
#pragma unroll
    for (int r = 0; r < 4; ++r) {
        float ig = sigm(vi[r]);
        float fg = sigm(vf[r]);
        float og = sigm(vo[r]);
        float gg = tanh_fast(vg[r]);
        nc[r] = fg * cin[r] + ig * gg;
        nh[r] = og * tanh_fast(nc[r]);
    }
    float4 h4 = {nh[0], nh[1], nh[2], nh[3]};
    float4 c4o = {nc[0], nc[1], nc[2], nc[3]};
    *(float4*)(out + (size_t)row * H_DIM + j0) = h4;
    *(float4*)(out + (size_t)B_DIM * H_DIM + (size_t)row * H_DIM + j0) = c4o;
}

// ---------- launch ----------
extern "C" void kernel_launch(void* const* d_in, const int* in_sizes, int n_in,
                              void* d_out, int out_size, void* d_ws, size_t ws_size,
                              hipStream_t stream) {
    const float* x  = (const float*)d_in[0];
    const float* ph = (const float*)d_in[1];
    const float* pc = (const float*)d_in[2];
    const float* Wx = (const float*)d_in[3];
    const float* Wh = (const float*)d_in[4];
    const float* b  = (const float*)d_in[5];
    const float* gm = (const float*)d_in[6];
    const float* bt = (const float*)d_in[7];
    float* out = (float*)d_out;

    char* ws = (char*)d_ws;
    u16* Abf = (u16*)ws;                               // 16 MiB: [4096][2048] bf16
    u16* Btb = (u16*)(ws + (size_t)16 * 1024 * 1024);  // 16 MiB: [4096][2048] bf16
    u16* aT  = (u16*)(ws + (size_t)32 * 1024 * 1024);  // 32 MiB: [4096][4096] bf16

    prep<<<dim3(4096 + 2048), dim3(256), 0, stream>>>(x, ph, Wx, Wh, Abf, Btb);
    gemm_bf16<<<dim3(32, 32), dim3(256), 0, stream>>>(Abf, Btb, b, aT);
    ln_lstm<<<dim3(4096), dim3(256), 0, stream>>>(aT, pc, gm, bt, out);
}

// Round 4
// 228.397 us; speedup vs baseline: 1.0493x; 1.0046x over previous
//
#include <hip/hip_runtime.h>
#include <hip/hip_bf16.h>
#include <stdint.h>

typedef unsigned short u16;
typedef __attribute__((ext_vector_type(8))) short short8;
typedef __attribute__((ext_vector_type(16))) float f32x16;

#define B_DIM 4096
#define D_DIM 1024
#define H_DIM 1024
#define K_DIM 2048   // D + H
#define N_DIM 4096   // 4H
#define LN_EPS 1e-5f

// ---------- helpers ----------
__device__ __forceinline__ u16 f2bf(float f) {
    union { float f; uint32_t u; } v; v.f = f;
    uint32_t u = v.u;
    uint32_t r = (u + 0x7FFFu + ((u >> 16) & 1u)) >> 16;  // RNE
    return (u16)r;
}
__device__ __forceinline__ float bf2f(u16 h) {
    union { uint32_t u; float f; } v; v.u = ((uint32_t)h) << 16;
    return v.f;
}
__device__ __forceinline__ void gld16(const u16* g, u16* l) {
    __builtin_amdgcn_global_load_lds(
        (const __attribute__((address_space(1))) void*)g,
        (__attribute__((address_space(3))) void*)l,
        16, 0, 0);
}
__device__ __forceinline__ float sigm(float x) { return 1.0f / (1.0f + __expf(-x)); }
__device__ __forceinline__ float tanh_fast(float x) { return 1.0f - 2.0f / (__expf(2.0f * x) + 1.0f); }

// ---------- kernel 1: fused prep ----------
__global__ __launch_bounds__(256) void prep(const float* __restrict__ x,
                                            const float* __restrict__ h,
                                            const float* __restrict__ Wx,
                                            const float* __restrict__ Wh,
                                            u16* __restrict__ A,
                                            u16* __restrict__ Bt) {
    __shared__ u16 tile[64 * 64];
    const int t = threadIdx.x;
    if (blockIdx.x < 4096) {
        int id = blockIdx.x * 256 + t;
        int row = id >> 8;
        int col = (id & 255) * 8;
        const float* src = (col < D_DIM) ? (x + (size_t)row * D_DIM + col)
                                         : (h + (size_t)row * H_DIM + (col - D_DIM));
        float4 v0 = ((const float4*)src)[0];
        float4 v1 = ((const float4*)src)[1];
        union { u16 us[8]; uint4 u; } p;
        p.us[0] = f2bf(v0.x); p.us[1] = f2bf(v0.y); p.us[2] = f2bf(v0.z); p.us[3] = f2bf(v0.w);
        p.us[4] = f2bf(v1.x); p.us[5] = f2bf(v1.y); p.us[6] = f2bf(v1.z); p.us[7] = f2bf(v1.w);
        *(uint4*)(A + (size_t)id * 8) = p.u;
    } else {
        const int v = blockIdx.x - 4096;       // 0..2047 = 64 x 32
        const int n0 = (v & 63) * 64;
        const int k0 = (v >> 6) * 64;
        const int kl  = t >> 4;                // 0..15
        const int nl4 = (t & 15) * 4;          // 0..60
#pragma unroll
        for (int it = 0; it < 4; ++it) {
            const int klocal = kl + it * 16;
            const int k = k0 + klocal;
            const float* src = (k < D_DIM) ? (Wx + (size_t)k * N_DIM)
                                           : (Wh + (size_t)(k - D_DIM) * N_DIM);
            float4 w = *(const float4*)(src + n0 + nl4);
            union { u16 us[4]; uint2 u; } p;
            p.us[0] = f2bf(w.x); p.us[1] = f2bf(w.y); p.us[2] = f2bf(w.z); p.us[3] = f2bf(w.w);
            const int swz = 8 * ((klocal >> 4) & 3);
            *(uint2*)(tile + klocal * 64 + (nl4 ^ swz)) = p.u;
        }
        __syncthreads();
        const int nl = t >> 2;
        const int kp = (t & 3) * 16;
        const int swz = 8 * (t & 3);
        union { u16 us[16]; uint4 q[2]; } o;
#pragma unroll
        for (int i = 0; i < 16; ++i)
            o.us[i] = tile[(kp + i) * 64 + (nl ^ swz)];
        u16* dst = Bt + (size_t)(n0 + nl) * K_DIM + k0 + kp;
        *(uint4*)dst = o.q[0];
        *(uint4*)(dst + 8) = o.q[1];
    }
}

// ---------- kernel 2: GEMM a = A @ Bt^T + bias -> bf16 [4096][4096] ----------
// 256x256 block, 4 waves, 128x128 per wave (4x4 of 32x32x16 MFMA), BK=64,
// double-buffered LDS (128 KB), 1 block/CU (grid 16x16 = 256 = #CUs).
// Prefetch of tile k+1 is issued right after the per-iteration barrier, so the
// barrier's vmcnt(0) drain overlaps the ~64-MFMA compute phase.
// LDS swizzle: row R (128 B = 8 x 16B blocks), LDS block kbl holds global
// k-block (kbl - perm(R)) & 7 with perm(R) = (R&7) + 2*((R>>3)&3); any
// 8-aligned lane group then covers all 8 bank-quads -> conflict-free.
__global__ __launch_bounds__(256, 1) void gemm_bf16(const u16* __restrict__ A,   // [4096][2048]
                                                    const u16* __restrict__ Bt,  // [4096][2048]
                                                    const float* __restrict__ bias,
                                                    u16* __restrict__ C) {       // [4096][4096]
    __shared__ u16 As[2][256 * 64];
    __shared__ u16 Bs[2][256 * 64];
    const int tid = threadIdx.x;
    const int wave = tid >> 6, lane = tid & 63;
    const int m0 = blockIdx.y * 256;
    const int n0 = blockIdx.x * 256;
    const int wm = (wave & 1) * 128;
    const int wn = (wave >> 1) * 128;

    f32x16 acc[4][4] = {};

    // staging: wave w, issue q (0..7), lane l covers row R = q*32 + w*8 + (l>>3),
    // LDS block kbl = l&7 -> global block (kbl - perm(R)) & 7; perm(R) = (l>>3) + 2w
    const int skc = (((lane & 7) - (lane >> 3) - 2 * wave + 32) & 7) * 8;
    const u16* aG = A  + (size_t)(m0 + wave * 8 + (lane >> 3)) * K_DIM + skc;
    const u16* bG = Bt + (size_t)(n0 + wave * 8 + (lane >> 3)) * K_DIM + skc;
    const int ldsOff = (wave * 8) * 64;

    // fragment read: row R = wm/wn + i*32 + lr -> perm(R) = (lr&7) + 2*(lr>>3)
    const int lr = lane & 31, half = lane >> 5;
    const int permR = ((lr & 7) + 2 * (lr >> 3)) & 7;

    for (int it = 0; it < K_DIM / 64 + 1; ++it) {
        // prefetch tile `it` into buffer it&1 (first iteration: initial fill)
        if (it < K_DIM / 64) {
            const int kt = it * 64;
            const int buf = it & 1;
            u16* aL = &As[buf][ldsOff];
            u16* bL = &Bs[buf][ldsOff];
#pragma unroll
            for (int q = 0; q < 8; ++q) {
                gld16(aG + kt + (size_t)q * 32 * K_DIM, aL + q * 32 * 64);
                gld16(bG + kt + (size_t)q * 32 * K_DIM, bL + q * 32 * 64);
            }
        }
        if (it == 0) { __syncthreads(); continue; }   // nothing to compute yet

        // compute on buffer (it-1)&1 while prefetch for `it` is in flight
        const int cbuf = (it - 1) & 1;
#pragma unroll
        for (int kk = 0; kk < 4; ++kk) {
            const int koff = (((kk * 2 + half) + permR) & 7) * 8;
            short8 af[4], bf[4];
#pragma unroll
            for (int i = 0; i < 4; ++i)
                af[i] = *(const short8*)(&As[cbuf][(wm + i * 32 + lr) * 64 + koff]);
#pragma unroll
            for (int j = 0; j < 4; ++j)
                bf[j] = *(const short8*)(&Bs[cbuf][(wn + j * 32 + lr) * 64 + koff]);
#pragma unroll
            for (int i = 0; i < 4; ++i)
#pragma unroll
                for (int j = 0; j < 4; ++j)
                    acc[i][j] = __builtin_amdgcn_mfma_f32_32x32x16_bf16(af[i], bf[j], acc[i][j], 0, 0, 0);
        }
        __syncthreads();   // drains prefetch vmcnt (had full compute phase to land)
    }

    // epilogue: 32x32 C/D layout col=lane&31, row=(reg&3)+8*(reg>>2)+4*(lane>>5)
#pragma unroll
    for (int i = 0; i < 4; ++i) {
#pragma unroll
        for (int j = 0; j < 4; ++j) {
            const int c = n0 + wn + 32 * j + lr;
            const float bb = bias[c];
#pragma unroll
            for (int reg = 0; reg < 16; ++reg) {
                const int row = m0 + wm + 32 * i + (reg & 3) + 8 * (reg >> 2) + 4 * half;
                C[(size_t)row * N_DIM + c] = f2bf(acc[i][j][reg] + bb);
            }
        }
    }
}

// ---------- kernel 3: LayerNorm + gates + cell update (single pass over aT) ----------
__global__ __launch_bounds__(256) void ln_lstm(const u16* __restrict__ aT,     // [4096][4096] bf16
                                               const float* __restrict__ pc,   // prev_c
                                               const float* __restrict__ gamma,
                                               const float* __restrict__ beta,
                                               float* __restrict__ out) {      // [h | c]
    const int row = blockIdx.x;
    const int t = threadIdx.x;
    const u16* ar = aT + (size_t)row * N_DIM;
    const int j0 = t * 4;

    union U2 { uint2 u; u16 us[4]; };
    U2 g4[4];
#pragma unroll
    for (int s = 0; s < 4; ++s) g4[s].u = *(const uint2*)(ar + s * H_DIM + j0);

    float sum = 0.f, ssq = 0.f;
#pragma unroll
    for (int s = 0; s < 4; ++s)
#pragma unroll
        for (int e = 0; e < 4; ++e) { float v = bf2f(g4[s].us[e]); sum += v; ssq += v * v; }

#pragma unroll
    for (int off = 32; off > 0; off >>= 1) {
        sum += __shfl_down(sum, off, 64);
        ssq += __shfl_down(ssq, off, 64);
    }
    __shared__ float red[8];
    if ((t & 63) == 0) { red[t >> 6] = sum; red[4 + (t >> 6)] = ssq; }
    __syncthreads();
    const float ts = red[0] + red[1] + red[2] + red[3];
    const float tq = red[4] + red[5] + red[6] + red[7];
    const float mu = ts * (1.0f / N_DIM);
    const float var = fmaxf(tq * (1.0f / N_DIM) - mu * mu, 0.0f);
    const float rs = rsqrtf(var + LN_EPS);

    float vi[4], vf[4], vo[4], vg[4];
    auto gate = [&](int s, float* v) {
        const int off = s * H_DIM;
        float4 gm = *(const float4*)(gamma + off + j0);
        float4 bt = *(const float4*)(beta + off + j0);
        v[0] = (bf2f(g4[s].us[0]) - mu) * rs * gm.x + bt.x;
        v[1] = (bf2f(g4[s].us[1]) - mu) * rs * gm.y + bt.y;
        v[2] = (bf2f(g4[s].us[2]) - mu) * rs * gm.z + bt.z;
        v[3] = (bf2f(g4[s].us[3]) - mu) * rs * gm.w + bt.w;
    };
    gate(0, vi); gate(1, vf); gate(2, vo); gate(3, vg);

    float4 c4 = *(const float4*)(pc + (size_t)row * H_DIM + j0);
    float cin[4] = {c4.x, c4.y, c4.z, c4.w};
    float nh[4], nc[4];
#pragma unroll
    for (int r = 0; r < 4; ++r) {
        float ig = sigm(vi[r]);
        float fg = sigm(vf[r]);
        float og = sigm(vo[r]);
        float gg = tanh_fast(vg[r]);
        nc[r] = fg * cin[r] + ig * gg;
        nh[r] = og * tanh_fast(nc[r]);
    }
    float4 h4 = {nh[0], nh[1], nh[2], nh[3]};
    float4 c4o = {nc[0], nc[1], nc[2], nc[3]};
    *(float4*)(out + (size_t)row * H_DIM + j0) = h4;
    *(float4*)(out + (size_t)B_DIM * H_DIM + (size_t)row * H_DIM + j0) = c4o;
}

// ---------- launch ----------
extern "C" void kernel_launch(void* const* d_in, const int* in_sizes, int n_in,
                              void* d_out, int out_size, void* d_ws, size_t ws_size,
                              hipStream_t stream) {
    const float* x  = (const float*)d_in[0];
    const float* ph = (const float*)d_in[1];
    const float* pc = (const float*)d_in[2];
    const float* Wx = (const float*)d_in[3];
    const float* Wh = (const float*)d_in[4];
    const float* b  = (const float*)d_in[5];
    const float* gm = (const float*)d_in[6];
    const float* bt = (const float*)d_in[7];
    float* out = (float*)d_out;

    char* ws = (char*)d_ws;
    u16* Abf = (u16*)ws;                               // 16 MiB: [4096][2048] bf16
    u16* Btb = (u16*)(ws + (size_t)16 * 1024 * 1024);  // 16 MiB: [4096][2048] bf16
    u16* aT  = (u16*)(ws + (size_t)32 * 1024 * 1024);  // 32 MiB: [4096][4096] bf16

    prep<<<dim3(4096 + 2048), dim3(256), 0, stream>>>(x, ph, Wx, Wh, Abf, Btb);
    gemm_bf16<<<dim3(16, 16), dim3(256), 0, stream>>>(Abf, Btb, b, aT);
    ln_lstm<<<dim3(4096), dim3(256), 0, stream>>>(aT, pc, gm, bt, out);
}

// Round 5
// 222.762 us; speedup vs baseline: 1.0758x; 1.0253x over previous
//
#include <hip/hip_runtime.h>
#include <hip/hip_bf16.h>
#include <stdint.h>

typedef unsigned short u16;
typedef __attribute__((ext_vector_type(8))) short short8;
typedef __attribute__((ext_vector_type(16))) float f32x16;

#define B_DIM 4096
#define D_DIM 1024
#define H_DIM 1024
#define K_DIM 2048   // D + H
#define N_DIM 4096   // 4H
#define LN_EPS 1e-5f

// ---------- helpers ----------
__device__ __forceinline__ u16 f2bf(float f) {
    union { float f; uint32_t u; } v; v.f = f;
    uint32_t u = v.u;
    uint32_t r = (u + 0x7FFFu + ((u >> 16) & 1u)) >> 16;  // RNE
    return (u16)r;
}
__device__ __forceinline__ float bf2f(u16 h) {
    union { uint32_t u; float f; } v; v.u = ((uint32_t)h) << 16;
    return v.f;
}
__device__ __forceinline__ void gld16(const u16* g, u16* l) {
    __builtin_amdgcn_global_load_lds(
        (const __attribute__((address_space(1))) void*)g,
        (__attribute__((address_space(3))) void*)l,
        16, 0, 0);
}
__device__ __forceinline__ float sigm(float x) { return 1.0f / (1.0f + __expf(-x)); }
__device__ __forceinline__ float tanh_fast(float x) { return 1.0f - 2.0f / (__expf(2.0f * x) + 1.0f); }

// ---------- kernel 1: fused prep ----------
__global__ __launch_bounds__(256) void prep(const float* __restrict__ x,
                                            const float* __restrict__ h,
                                            const float* __restrict__ Wx,
                                            const float* __restrict__ Wh,
                                            u16* __restrict__ A,
                                            u16* __restrict__ Bt) {
    __shared__ u16 tile[64 * 64];
    const int t = threadIdx.x;
    if (blockIdx.x < 4096) {
        int id = blockIdx.x * 256 + t;
        int row = id >> 8;
        int col = (id & 255) * 8;
        const float* src = (col < D_DIM) ? (x + (size_t)row * D_DIM + col)
                                         : (h + (size_t)row * H_DIM + (col - D_DIM));
        float4 v0 = ((const float4*)src)[0];
        float4 v1 = ((const float4*)src)[1];
        union { u16 us[8]; uint4 u; } p;
        p.us[0] = f2bf(v0.x); p.us[1] = f2bf(v0.y); p.us[2] = f2bf(v0.z); p.us[3] = f2bf(v0.w);
        p.us[4] = f2bf(v1.x); p.us[5] = f2bf(v1.y); p.us[6] = f2bf(v1.z); p.us[7] = f2bf(v1.w);
        *(uint4*)(A + (size_t)id * 8) = p.u;
    } else {
        const int v = blockIdx.x - 4096;       // 0..2047 = 64 x 32
        const int n0 = (v & 63) * 64;
        const int k0 = (v >> 6) * 64;
        const int kl  = t >> 4;                // 0..15
        const int nl4 = (t & 15) * 4;          // 0..60
#pragma unroll
        for (int it = 0; it < 4; ++it) {
            const int klocal = kl + it * 16;
            const int k = k0 + klocal;
            const float* src = (k < D_DIM) ? (Wx + (size_t)k * N_DIM)
                                           : (Wh + (size_t)(k - D_DIM) * N_DIM);
            float4 w = *(const float4*)(src + n0 + nl4);
            union { u16 us[4]; uint2 u; } p;
            p.us[0] = f2bf(w.x); p.us[1] = f2bf(w.y); p.us[2] = f2bf(w.z); p.us[3] = f2bf(w.w);
            const int swz = 8 * ((klocal >> 4) & 3);
            *(uint2*)(tile + klocal * 64 + (nl4 ^ swz)) = p.u;
        }
        __syncthreads();
        const int nl = t >> 2;
        const int kp = (t & 3) * 16;
        const int swz = 8 * (t & 3);
        union { u16 us[16]; uint4 q[2]; } o;
#pragma unroll
        for (int i = 0; i < 16; ++i)
            o.us[i] = tile[(kp + i) * 64 + (nl ^ swz)];
        u16* dst = Bt + (size_t)(n0 + nl) * K_DIM + k0 + kp;
        *(uint4*)dst = o.q[0];
        *(uint4*)(dst + 8) = o.q[1];
    }
}

// ---------- kernel 2: GEMM a = A @ Bt^T + bias -> bf16 [4096][4096] ----------
// 256x256 block, 4 waves, 128x128 per wave (4x4 of 32x32x16), BK=64, dbuf.
// LDS geometry = round-2's measured-zero-conflict class:
//   each BK=64 tile stored as 2 half-panels (hp = k/32) of [256 rows][32 u16];
//   row stride 64 B -> bank half = row parity; 4 16B-blocks per row, stored
//   block s holds global block g = (s - (row>>1)) & 3 (row = local row & 31).
//   Fragment read s = (g + (lr>>1)) & 3 -> every aligned 8-lane group covers
//   all 8 bank quads (same pattern class that measured 0 conflicts in r2).
__global__ __launch_bounds__(256, 1) void gemm_bf16(const u16* __restrict__ A,   // [4096][2048]
                                                    const u16* __restrict__ Bt,  // [4096][2048]
                                                    const float* __restrict__ bias,
                                                    u16* __restrict__ C) {       // [4096][4096]
    __shared__ u16 As[2][16384];   // [buf][hp*8192 + row*32 + s*8]
    __shared__ u16 Bs[2][16384];
    const int tid = threadIdx.x;
    const int wave = tid >> 6, lane = tid & 63;
    const int m0 = blockIdx.y * 256;
    const int n0 = blockIdx.x * 256;
    const int wm = (wave & 1) * 128;
    const int wn = (wave >> 1) * 128;

    f32x16 acc[4][4] = {};

    // staging: chunk = 1 KB = 16 rows x 32 u16. Per matrix 32 chunks (hp,c),
    // wave handles ch = wave*8+q (q=0..7): hp = ch>>4, c = ch&15.
    // lane l -> row c*16 + (l>>2); stored block l&3 holds global block
    // perm = ((l&3) - (l>>3)) & 3  [(row&31)>>1 = (c&1)*8 + (l>>3) == l>>3 mod 4]
    const int perm = ((lane & 3) - (lane >> 3)) & 3;
    const int vofs = (lane >> 2) * K_DIM + perm * 8;   // per-lane global offset
    const int lr = lane & 31, half = lane >> 5;

    for (int it = 0; it < K_DIM / 64 + 1; ++it) {
        if (it < K_DIM / 64) {
            const int kt = it * 64;
            const int buf = it & 1;
#pragma unroll
            for (int q = 0; q < 8; ++q) {
                const int ch = wave * 8 + q;
                const int hp = ch >> 4, c = ch & 15;
                const int so = (c * 16) * K_DIM + kt + hp * 32;   // wave-uniform
                const int ldso = hp * 8192 + c * 512;
                gld16(A  + (size_t)m0 * K_DIM + so + vofs, &As[buf][ldso]);
                gld16(Bt + (size_t)n0 * K_DIM + so + vofs, &Bs[buf][ldso]);
            }
        }
        if (it == 0) { __syncthreads(); continue; }

        const int cbuf = (it - 1) & 1;
#pragma unroll
        for (int kk = 0; kk < 4; ++kk) {
            const int hp = kk >> 1;
            const int s = (((kk & 1) * 2 + half) + (lr >> 1)) & 3;
            const int ko = hp * 8192 + s * 8;
            short8 af[4], bf[4];
#pragma unroll
            for (int i = 0; i < 4; ++i)
                af[i] = *(const short8*)(&As[cbuf][ko + (wm + i * 32 + lr) * 32]);
#pragma unroll
            for (int j = 0; j < 4; ++j)
                bf[j] = *(const short8*)(&Bs[cbuf][ko + (wn + j * 32 + lr) * 32]);
#pragma unroll
            for (int i = 0; i < 4; ++i)
#pragma unroll
                for (int j = 0; j < 4; ++j)
                    acc[i][j] = __builtin_amdgcn_mfma_f32_32x32x16_bf16(af[i], bf[j], acc[i][j], 0, 0, 0);
        }
        __syncthreads();   // prefetch for `it` drains here, after full compute phase
    }

    // epilogue: 32x32 C/D layout col=lane&31, row=(reg&3)+8*(reg>>2)+4*(lane>>5)
#pragma unroll
    for (int i = 0; i < 4; ++i) {
#pragma unroll
        for (int j = 0; j < 4; ++j) {
            const int c = n0 + wn + 32 * j + lr;
            const float bb = bias[c];
#pragma unroll
            for (int reg = 0; reg < 16; ++reg) {
                const int row = m0 + wm + 32 * i + (reg & 3) + 8 * (reg >> 2) + 4 * half;
                C[(size_t)row * N_DIM + c] = f2bf(acc[i][j][reg] + bb);
            }
        }
    }
}

// ---------- kernel 3: LayerNorm + gates + cell update (single pass over aT) ----------
__global__ __launch_bounds__(256) void ln_lstm(const u16* __restrict__ aT,     // [4096][4096] bf16
                                               const float* __restrict__ pc,   // prev_c
                                               const float* __restrict__ gamma,
                                               const float* __restrict__ beta,
                                               float* __restrict__ out) {      // [h | c]
    const int row = blockIdx.x;
    const int t = threadIdx.x;
    const u16* ar = aT + (size_t)row * N_DIM;
    const int j0 = t * 4;

    union U2 { uint2 u; u16 us[4]; };
    U2 g4[4];
#pragma unroll
    for (int s = 0; s < 4; ++s) g4[s].u = *(const uint2*)(ar + s * H_DIM + j0);

    float sum = 0.f, ssq = 0.f;
#pragma unroll
    for (int s = 0; s < 4; ++s)
#pragma unroll
        for (int e = 0; e < 4; ++e) { float v = bf2f(g4[s].us[e]); sum += v; ssq += v * v; }

#pragma unroll
    for (int off = 32; off > 0; off >>= 1) {
        sum += __shfl_down(sum, off, 64);
        ssq += __shfl_down(ssq, off, 64);
    }
    __shared__ float red[8];
    if ((t & 63) == 0) { red[t >> 6] = sum; red[4 + (t >> 6)] = ssq; }
    __syncthreads();
    const float ts = red[0] + red[1] + red[2] + red[3];
    const float tq = red[4] + red[5] + red[6] + red[7];
    const float mu = ts * (1.0f / N_DIM);
    const float var = fmaxf(tq * (1.0f / N_DIM) - mu * mu, 0.0f);
    const float rs = rsqrtf(var + LN_EPS);

    float vi[4], vf[4], vo[4], vg[4];
    auto gate = [&](int s, float* v) {
        const int off = s * H_DIM;
        float4 gm = *(const float4*)(gamma + off + j0);
        float4 bt = *(const float4*)(beta + off + j0);
        v[0] = (bf2f(g4[s].us[0]) - mu) * rs * gm.x + bt.x;
        v[1] = (bf2f(g4[s].us[1]) - mu) * rs * gm.y + bt.y;
        v[2] = (bf2f(g4[s].us[2]) - mu) * rs * gm.z + bt.z;
        v[3] = (bf2f(g4[s].us[3]) - mu) * rs * gm.w + bt.w;
    };
    gate(0, vi); gate(1, vf); gate(2, vo); gate(3, vg);

    float4 c4 = *(const float4*)(pc + (size_t)row * H_DIM + j0);
    float cin[4] = {c4.x, c4.y, c4.z, c4.w};
    float nh[4], nc[4];
#pragma unroll
    for (int r = 0; r < 4; ++r) {
        float ig = sigm(vi[r]);
        float fg = sigm(vf[r]);
        float og = sigm(vo[r]);
        float gg = tanh_fast(vg[r]);
        nc[r] = fg * cin[r] + ig * gg;
        nh[r] = og * tanh_fast(nc[r]);
    }
    float4 h4 = {nh[0], nh[1], nh[2], nh[3]};
    float4 c4o = {nc[0], nc[1], nc[2], nc[3]};
    *(float4*)(out + (size_t)row * H_DIM + j0) = h4;
    *(float4*)(out + (size_t)B_DIM * H_DIM + (size_t)row * H_DIM + j0) = c4o;
}

// ---------- launch ----------
extern "C" void kernel_launch(void* const* d_in, const int* in_sizes, int n_in,
                              void* d_out, int out_size, void* d_ws, size_t ws_size,
                              hipStream_t stream) {
    const float* x  = (const float*)d_in[0];
    const float* ph = (const float*)d_in[1];
    const float* pc = (const float*)d_in[2];
    const float* Wx = (const float*)d_in[3];
    const float* Wh = (const float*)d_in[4];
    const float* b  = (const float*)d_in[5];
    const float* gm = (const float*)d_in[6];
    const float* bt = (const float*)d_in[7];
    float* out = (float*)d_out;

    char* ws = (char*)d_ws;
    u16* Abf = (u16*)ws;                               // 16 MiB: [4096][2048] bf16
    u16* Btb = (u16*)(ws + (size_t)16 * 1024 * 1024);  // 16 MiB: [4096][2048] bf16
    u16* aT  = (u16*)(ws + (size_t)32 * 1024 * 1024);  // 32 MiB: [4096][4096] bf16

    prep<<<dim3(4096 + 2048), dim3(256), 0, stream>>>(x, ph, Wx, Wh, Abf, Btb);
    gemm_bf16<<<dim3(16, 16), dim3(256), 0, stream>>>(Abf, Btb, b, aT);
    ln_lstm<<<dim3(4096), dim3(256), 0, stream>>>(aT, pc, gm, bt, out);
}